// Round 11
// baseline (3690.654 us; speedup 1.0000x reference)
//
#include <hip/hip_runtime.h>
#include <cstdint>
#include <cstddef>

// SingleLayerLSTM: B=128, T=2048, D=64, H=256, O=32.
// v20: MFMA rewrite. R10's null proved the VALU path is exhausted: busy
// ~1900cy/step IS the v_dot2 issue stream (MfmaUtil was 0.0 all session).
// Batch 16 items per group so gates become real matrix work:
//  - 8 groups x 2 blocks (width-2 convoy, R8-proven). Block: 128 ch x 16
//    items, 512 thr. Wave w owns 16 ch x 4 gates = 4 col-tiles; K=320 =
//    10 K-tiles of mfma_f32_16x16x32_f16.
//  - B-frags (weights) register-resident: 4 gates x 10 kt x 8 f16 = 160
//    VGPR/lane. A-frags (activations x=[u64|h256] fp16, row-padded to 328
//    for bank spread) from LDS, one ds_read_b128 each.
//  - Layout safety: k-permutation cancels if A and B use the SAME k
//    convention (k is summed; A/B k-maps symmetric). Only relies on
//    HW-verified A-row/B-col = lane&15 and C/D row=(lane>>4)*4+reg,
//    col=lane&15 (m89, dtype-independent).
//  - Lane holds f,i,z,r for 4 (item,ch) pairs -> activations lane-local,
//    NO cross-lane reduce at all.
//  - UOWN/PDOT split kept in MFMA form: own 6 K-tiles (u 2 + own-h 4) in
//    shadow D; partner 4 K-tiles on the A-path. Exchange identical to
//    v19 (tagged u32 xh[2][128][256], agent relaxed, 0xAA poison -> no
//    init, replay-safe); poll = 1 dwordx4/lane (4 tags), spec-issued at
//    D-start, checked at E, per-lane retry. Raw lgkm barriers.
//  - y: wave 0 MFMA (8 kt, Wout frags in LDS) in shadow, one step delayed.
// Grid 16 blocks: pair (g, g+8) shares bid%8 -> same XCD.

#define HH 256
#define DD 64
#define TT 2048
#define OO 32
#define XROW 328   // 320 + 8 fp16 pad: row stride 656B -> 2-way banks (free)
#define GI 16      // items per group

typedef _Float16 f16x8 __attribute__((ext_vector_type(8)));
typedef float    f32x4 __attribute__((ext_vector_type(4)));
typedef unsigned u32x4 __attribute__((ext_vector_type(4)));
typedef unsigned short u16x4 __attribute__((ext_vector_type(4)));

__device__ __forceinline__ f32x4 mfma16(f16x8 a, f16x8 b, f32x4 c) {
  return __builtin_amdgcn_mfma_f32_16x16x32_f16(a, b, c, 0, 0, 0);
}

__device__ __forceinline__ float frcp(float x) { return __builtin_amdgcn_rcpf(x); }
__device__ __forceinline__ float sigm(float x)  { return frcp(1.0f + __expf(-x)); }
__device__ __forceinline__ float tanhf_(float x){ return 1.0f - 2.0f * frcp(1.0f + __expf(2.0f * x)); }

// LDS-only drain + raw barrier: global loads/stores stay in flight.
#define BAR_LGKM() do { \
  asm volatile("s_waitcnt lgkmcnt(0)" ::: "memory"); \
  __builtin_amdgcn_s_barrier(); \
  asm volatile("" ::: "memory"); \
} while (0)

// system-scope dwordx4 load + wait (retry path)
__device__ __forceinline__ u32x4 ld4_sys(const unsigned* p) {
  u32x4 v;
  asm volatile("global_load_dwordx4 %0, %1, off sc0 sc1\n\ts_waitcnt vmcnt(0)"
               : "=v"(v) : "v"(p) : "memory");
  return v;
}

// one K-tile of the gate GEMM: a-frag from XP at compile-time KT, all 4 gates.
// KT must be a literal so wB*[KT] stays register-indexed (rule: no runtime
// indexing of register arrays).
#define GKT(XP, KT) do { \
  const f16x8 a_ = *(const f16x8*)&(XP)[aoff + (KT) * 32]; \
  acc0 = mfma16(a_, wB0[KT], acc0); \
  acc1 = mfma16(a_, wB1[KT], acc1); \
  acc2 = mfma16(a_, wB2[KT], acc2); \
  acc3 = mfma16(a_, wB3[KT], acc3); \
} while (0)

__global__ __launch_bounds__(512, 2)
void lstm_mfma(const float* __restrict__ u,    const float* __restrict__ x0,
               const float* __restrict__ kfiz, const float* __restrict__ bfiz,
               const float* __restrict__ kr,   const float* __restrict__ br,
               const float* __restrict__ wout, const float* __restrict__ bout,
               float* __restrict__ out, unsigned* __restrict__ xh)
{
  const int tid = threadIdx.x;
  const int bid = blockIdx.x;
  const int g   = bid & 7;          // group [0,8): items 16g..16g+15
  const int hf  = bid >> 3;         // half  [0,2): channels [hf*128,+128)
  const int g16 = g * GI;
  const int l   = tid & 63;         // lane
  const int w   = tid >> 6;         // wave [0,8)
  const int chl = w * 16 + (l & 15);        // channel within half [0,128)
  const int cgl = hf * 128 + chl;           // global channel
  const int itl = (l >> 4) * 4;             // first of this lane's 4 items
  const int aoff = (l & 15) * XROW + (l >> 4) * 8;       // A-frag base (item=l&15)
  const int yoff = (l & 15) * XROW + 64 + (l >> 4) * 8;  // y A-frag base

  // x[p][item*XROW + dim]: dim [0,64)=u, [64,320)=h(global ch+64)
  __shared__ __align__(16) _Float16 x[2][GI * XROW];
  __shared__ __align__(16) f16x8 wy[8][64];   // Wout B-frags for wave 0

  // ---- register-resident gate B-frags: wB[gate][kt], k = kt*32+(l>>4)*8+j,
  //      col = gate-col(cgl). Same k-convention as A-frags -> layout-safe.
  f16x8 wB0[10], wB1[10], wB2[10], wB3[10];
#pragma unroll
  for (int kt = 0; kt < 10; ++kt) {
    f16x8 v0, v1, v2, v3;
#pragma unroll
    for (int j = 0; j < 8; ++j) {
      const int k = kt * 32 + (l >> 4) * 8 + j;
      v0[j] = (_Float16)kfiz[(size_t)k * (3 * HH) + 0 * HH + cgl];
      v1[j] = (_Float16)kfiz[(size_t)k * (3 * HH) + 1 * HH + cgl];
      v2[j] = (_Float16)kfiz[(size_t)k * (3 * HH) + 2 * HH + cgl];
      v3[j] = (_Float16)kr  [(size_t)k * HH + cgl];
    }
    wB0[kt] = v0; wB1[kt] = v1; wB2[kt] = v2; wB3[kt] = v3;
  }
  const float bf_ = bfiz[0 * HH + cgl];
  const float bi_ = bfiz[1 * HH + cgl];
  const float bz_ = bfiz[2 * HH + cgl];
  const float br_ = br[cgl];
  const float boV = bout[hf * 16 + (l & 15)];

  // ---- Wout B-frags -> LDS (8 kt x 64 lanes), same k-convention ----
  {
    const int kt = tid >> 6, ll = tid & 63;
    f16x8 v;
#pragma unroll
    for (int j = 0; j < 8; ++j)
      v[j] = (_Float16)wout[(size_t)(kt * 32 + (ll >> 4) * 8 + j) * OO + hf * 16 + (ll & 15)];
    wy[kt][ll] = v;
  }

  // ---- x[0] init: h0 (full 256) + u_0 ----
  {
    const int it = tid >> 5, c8 = (tid & 31) * 8;
    f16x8 h8;
#pragma unroll
    for (int j = 0; j < 8; ++j)
      h8[j] = (_Float16)x0[(size_t)(g16 + it) * 512 + c8 + j];
    *(f16x8*)&x[0][it * XROW + 64 + c8] = h8;
  }
  const float* up = u + ((size_t)(g16 + (tid >> 4)) * TT) * DD + (tid & 15) * 4;
  if (tid < 256) {
    const float4 uv = *(const float4*)up;
    u16x4 w4;
    w4.x = __builtin_bit_cast(unsigned short, (_Float16)uv.x);
    w4.y = __builtin_bit_cast(unsigned short, (_Float16)uv.y);
    w4.z = __builtin_bit_cast(unsigned short, (_Float16)uv.z);
    w4.w = __builtin_bit_cast(unsigned short, (_Float16)uv.w);
    *(u16x4*)&x[0][(tid >> 4) * XROW + (tid & 15) * 4] = w4;
  }

  // ---- c state: 4 items x own channel ----
  float cs[4];
#pragma unroll
  for (int r = 0; r < 4; ++r)
    cs[r] = x0[(size_t)(g16 + itl + r) * 512 + 256 + cgl];

  // ---- hoisted exchange pointers ----
  unsigned* pubp = xh + (size_t)(g16 + itl) * 256 + cgl;              // +r*256
  const int pch = (1 - hf) * 128 + (tid & 31) * 4;                    // partner ch
  const unsigned* pfb = xh + (size_t)(g16 + (tid >> 5)) * 256 + pch;  // poll
  const int imp_off = (tid >> 5) * XROW + 64 + pch;                   // LDS dest
  float* outp = out + ((size_t)(g16 + itl) * TT) * OO + hf * 16 + (l & 15);

  __syncthreads();

  // ---- prologue: own+u K-tiles for step 0 from x[0] ----
  f32x4 acc0 = {0.f, 0.f, 0.f, 0.f}, acc1 = acc0, acc2 = acc0, acc3 = acc0;
  {
    const _Float16* xp = &x[0][0];
    GKT(xp, 0); GKT(xp, 1);
    if (hf == 0) { GKT(xp, 2); GKT(xp, 3); GKT(xp, 4); GKT(xp, 5); }
    else         { GKT(xp, 6); GKT(xp, 7); GKT(xp, 8); GKT(xp, 9); }
  }

  for (int s = 0; s < TT; ++s) {
    const int cur = s & 1, nxt = cur ^ 1;
    const _Float16* xc = &x[cur][0];
    _Float16* xn = &x[nxt][0];
    const size_t xoff = (size_t)nxt << 15;   // parity offset in xh (u32 words)
    const unsigned want = (unsigned)(s + 1);

    // ---- A: partner K-tiles (4) ----
    if (hf == 0) { GKT(xc, 6); GKT(xc, 7); GKT(xc, 8); GKT(xc, 9); }
    else         { GKT(xc, 2); GKT(xc, 3); GKT(xc, 4); GKT(xc, 5); }

    // ---- B: activations, lane-local (4 items x own channel) ----
    float hn[4];
#pragma unroll
    for (int r = 0; r < 4; ++r) {
      const float fv = sigm(acc0[r] + bf_);
      const float iv = sigm(acc1[r] + bi_);
      const float zv = sigm(acc2[r] + bz_);
      const float rv = tanhf_(acc3[r] + br_);
      cs[r] = fv * cs[r] + iv * rv;
      hn[r] = zv * tanhf_(cs[r]);
    }

    // ---- C: publish (4 tagged u32) + own-h LDS + u_{s+1} stage ----
#pragma unroll
    for (int r = 0; r < 4; ++r) {
      const _Float16 hh = (_Float16)hn[r];
      xn[(itl + r) * XROW + 64 + cgl] = hh;
      __hip_atomic_store(pubp + xoff + r * 256,
                         (want << 16) | (unsigned)__builtin_bit_cast(unsigned short, hh),
                         __ATOMIC_RELAXED, __HIP_MEMORY_SCOPE_AGENT);
    }
    if (tid < 256 && s + 1 < TT) {
      const float4 uv = *(const float4*)&up[(size_t)(s + 1) * DD];
      u16x4 w4;
      w4.x = __builtin_bit_cast(unsigned short, (_Float16)uv.x);
      w4.y = __builtin_bit_cast(unsigned short, (_Float16)uv.y);
      w4.z = __builtin_bit_cast(unsigned short, (_Float16)uv.z);
      w4.w = __builtin_bit_cast(unsigned short, (_Float16)uv.w);
      *(u16x4*)&xn[(tid >> 4) * XROW + (tid & 15) * 4] = w4;
    }
    BAR_LGKM();   // B1: own-h + u visible for D's own K-tiles

    // ---- D: spec poll first; y_{s-1} (wave 0); own K-tiles for s+1 ----
    u32x4 pv;
    asm volatile("global_load_dwordx4 %0, %1, off sc0 sc1"
                 : "=v"(pv) : "v"(pfb + xoff));
    if (w == 0 && s >= 1) {
      f32x4 ay = {0.f, 0.f, 0.f, 0.f};
#pragma unroll
      for (int kt = 0; kt < 8; ++kt) {
        const f16x8 a_ = *(const f16x8*)&xc[yoff + kt * 32];
        ay = mfma16(a_, wy[kt][l], ay);
      }
#pragma unroll
      for (int r = 0; r < 4; ++r)
        outp[((size_t)r * TT + (s - 1)) * OO] = ay[r] + boV;
    }
    if (s + 1 < TT) {
      acc0 = f32x4{0.f, 0.f, 0.f, 0.f}; acc1 = acc0; acc2 = acc0; acc3 = acc0;
      GKT(xn, 0); GKT(xn, 1);
      if (hf == 0) { GKT(xn, 2); GKT(xn, 3); GKT(xn, 4); GKT(xn, 5); }
      else         { GKT(xn, 6); GKT(xn, 7); GKT(xn, 8); GKT(xn, 9); }
    }

    // ---- E: check spec (4 tags); per-lane retry; import -> LDS ----
    {
      asm volatile("s_waitcnt vmcnt(0)" : "+v"(pv) :: "memory");
      while (!((pv.x >> 16) == want && (pv.y >> 16) == want &&
               (pv.z >> 16) == want && (pv.w >> 16) == want))
        pv = ld4_sys(pfb + xoff);
      u16x4 hv;
      hv.x = (unsigned short)pv.x; hv.y = (unsigned short)pv.y;
      hv.z = (unsigned short)pv.z; hv.w = (unsigned short)pv.w;
      *(u16x4*)&xn[imp_off] = hv;
    }
    BAR_LGKM();   // B2: partner import visible for next A
  }

  // ---- epilogue: y_{TT-1} from x[0] (h(TT) complete after last E) ----
  if (w == 0) {
    const _Float16* xe = &x[0][0];
    f32x4 ay = {0.f, 0.f, 0.f, 0.f};
#pragma unroll
    for (int kt = 0; kt < 8; ++kt) {
      const f16x8 a_ = *(const f16x8*)&xe[yoff + kt * 32];
      ay = mfma16(a_, wy[kt][l], ay);
    }
#pragma unroll
    for (int r = 0; r < 4; ++r)
      outp[((size_t)r * TT + (TT - 1)) * OO] = ay[r] + boV;
  }
}

extern "C" void kernel_launch(void* const* d_in, const int* in_sizes, int n_in,
                              void* d_out, int out_size, void* d_ws, size_t ws_size,
                              hipStream_t stream) {
  const float* u    = (const float*)d_in[0];
  const float* x0   = (const float*)d_in[1];
  const float* kfiz = (const float*)d_in[2];
  const float* bfiz = (const float*)d_in[3];
  const float* kr   = (const float*)d_in[4];
  const float* br   = (const float*)d_in[5];
  const float* wout = (const float*)d_in[6];
  const float* bout = (const float*)d_in[7];
  float* out = (float*)d_out;
  // ws: xh[2 parity][128 item][256 ch] u32 = 256 KB. Word = tag<<16 | fp16.
  // 0xAAAA poison tag never matches a version in [1,2048] -> no init,
  // graph-replay safe (unchanged from v18/v19).
  unsigned* xh = (unsigned*)d_ws;
  lstm_mfma<<<dim3(16), dim3(512), 0, stream>>>(
      u, x0, kfiz, bfiz, kr, br, wout, bout, out, xh);
}